// Round 16
// baseline (384.850 us; speedup 1.0000x reference)
//
#include <hip/hip_runtime.h>
#include <math.h>

#define DIM 4096
#define NH 32
#define NKV 8
#define HD 128
#define NREP 4
#define SPLITMAX 256

typedef float f32x4 __attribute__((ext_vector_type(4)));

// ---------------------------------------------------------------------------
// Kernel 1: q/k/v GEMV + fused RoPE.
// ---------------------------------------------------------------------------
__global__ __launch_bounds__(256) void qkv_rope_kernel(
    const float* __restrict__ x, const float* __restrict__ fc,
    const float* __restrict__ fs, const float* __restrict__ wq,
    const float* __restrict__ wk, const float* __restrict__ wv,
    float* __restrict__ q_rope, float* __restrict__ k_new,
    float* __restrict__ v_new) {
  int wave = blockIdx.x * 4 + (threadIdx.x >> 6);
  int lane = threadIdx.x & 63;
  const float* W;
  float* dst;
  int r0;
  bool rope;
  if (wave < 2048) {            // q: 4096 rows
    W = wq; dst = q_rope; r0 = wave * 2; rope = true;
  } else if (wave < 2560) {     // k: 1024 rows
    W = wk; dst = k_new; r0 = (wave - 2048) * 2; rope = true;
  } else {                      // v: 1024 rows
    W = wv; dst = v_new; r0 = (wave - 2560) * 2; rope = false;
  }
  const float4* x4 = (const float4*)x;
  const float4* w0 = (const float4*)(W + (size_t)r0 * DIM);
  const float4* w1 = (const float4*)(W + (size_t)(r0 + 1) * DIM);
  float a0 = 0.f, a1 = 0.f;
#pragma unroll 4
  for (int c = lane; c < DIM / 4; c += 64) {
    float4 xv = x4[c];
    float4 u = w0[c];
    float4 v = w1[c];
    a0 += xv.x * u.x + xv.y * u.y + xv.z * u.z + xv.w * u.w;
    a1 += xv.x * v.x + xv.y * v.y + xv.z * v.z + xv.w * v.w;
  }
  for (int off = 32; off > 0; off >>= 1) {
    a0 += __shfl_down(a0, off, 64);
    a1 += __shfl_down(a1, off, 64);
  }
  if (lane == 0) {
    if (rope) {
      int j = (r0 & (HD - 1)) >> 1;
      float c = fc[j], s = fs[j];
      dst[r0]     = a0 * c - a1 * s;
      dst[r0 + 1] = a0 * s + a1 * c;
    } else {
      dst[r0]     = a0;
      dst[r0 + 1] = a1;
    }
  }
}

#define LD4(p) (*(const float4*)(p))
// non-temporal load: bypass LLC allocation for the streaming K/V cache
// (R15: 96.5 -> 92.8 us; KV consumption ~3.1 -> ~4.3 TB/s).
#define NT4(p) (__builtin_nontemporal_load((const f32x4*)(p)))

#define DOT4(sv, h)                                                         \
  sv = A.x * qf[h][0] + A.y * qf[h][1] + A.z * qf[h][2] + A.w * qf[h][3] +  \
       B.x * qf[h][4] + B.y * qf[h][5] + B.z * qf[h][6] + B.w * qf[h][7];

#define PV8(h, e)                                                           \
  acc[h][0] += (e)*VA.x; acc[h][1] += (e)*VA.y;                             \
  acc[h][2] += (e)*VA.z; acc[h][3] += (e)*VA.w;                             \
  acc[h][4] += (e)*VB.x; acc[h][5] += (e)*VB.y;                             \
  acc[h][6] += (e)*VB.z; acc[h][7] += (e)*VB.w;

// One position-step: K-dots for 4 heads, 5-shuffle transposed reduce,
// 3-shuffle broadcast, exp (fixed m=0 reference), PV accumulate.
#define STEP(KA_, KB_, VA_, VB_, VALID)                                     \
  {                                                                         \
    auto A = KA_; auto B = KB_;                                             \
    float s0, s1, s2, s3;                                                   \
    DOT4(s0, 0); DOT4(s1, 1); DOT4(s2, 2); DOT4(s3, 3);                     \
    float pp = hi8 ? s2 : s0, pq = hi8 ? s0 : s2;                           \
    pp += __shfl_xor(pq, 8, 64);                                            \
    float rr = hi8 ? s3 : s1, rs = hi8 ? s1 : s3;                           \
    rr += __shfl_xor(rs, 8, 64);                                            \
    float u = hi4 ? rr : pp, uvx = hi4 ? pp : rr;                           \
    u += __shfl_xor(uvx, 4, 64);                                            \
    u += __shfl_xor(u, 1, 64);                                              \
    u += __shfl_xor(u, 2, 64);                                              \
    float u4 = __shfl_xor(u, 4, 64);                                        \
    float u8 = __shfl_xor(u, 8, 64);                                        \
    float u12 = __shfl_xor(u4, 8, 64);                                      \
    float q0 = hi4 ? u4 : u,   q1 = hi4 ? u : u4;                           \
    float q2 = hi4 ? u12 : u8, q3 = hi4 ? u8 : u12;                         \
    float w0 = hi8 ? q2 : q0, w1 = hi8 ? q3 : q1;                           \
    float w2 = hi8 ? q0 : q2, w3 = hi8 ? q1 : q3;                           \
    float e0 = __expf((VALID) ? w0 * scale : -1e30f);                       \
    float e1 = __expf((VALID) ? w1 * scale : -1e30f);                       \
    float e2 = __expf((VALID) ? w2 * scale : -1e30f);                       \
    float e3 = __expf((VALID) ? w3 * scale : -1e30f);                       \
    lsum[0] += e0; lsum[1] += e1; lsum[2] += e2; lsum[3] += e3;             \
    auto VA = VA_; auto VB = VB_;                                           \
    PV8(0, e0) PV8(1, e1) PV8(2, e2) PV8(3, e3)                             \
  }

// ---------------------------------------------------------------------------
// Kernel 2: flash-decode partials (m=0 reference, validated R4-R15).
// R15 vehicle (nt loads) + occupancy doubled: launch_bounds(256,8) at
// VGPR<=64 -> 8 blocks/CU; rsplit 256 -> grid 2048.
// ---------------------------------------------------------------------------
__global__ __launch_bounds__(256, 8) void attn_partial_kernel(
    const float* __restrict__ q_rope, const float* __restrict__ k_cache,
    const float* __restrict__ v_cache, const float* __restrict__ k_new,
    const float* __restrict__ v_new, float* __restrict__ partial_m,
    float* __restrict__ partial_l, float* __restrict__ partial_o,
    int start_pos, int T, int CH, int rsplit) {
  int g = blockIdx.x % NKV;
  int split = blockIdx.x / NKV;
  int t0 = split * CH;
  int tid = threadIdx.x;
  int wvi = tid >> 6;
  int lane = tid & 63;
  int grp = lane >> 4;
  int lig = lane & 15;
  int tl0 = wvi * 4 + grp;
  int dbase = lig * 8;
  bool hi8 = (lig & 8) != 0, hi4 = (lig & 4) != 0;

  __shared__ float s_wacc[4][4][HD];
  __shared__ float s_wl[4][4];

  float qf[4][8];
#pragma unroll
  for (int h = 0; h < 4; ++h)
#pragma unroll
    for (int e = 0; e < 8; ++e)
      qf[h][e] = q_rope[(g * NREP + h) * HD + dbase + e];

  float lsum[4] = {0.f, 0.f, 0.f, 0.f};
  float acc[4][8];
#pragma unroll
  for (int h = 0; h < 4; ++h)
#pragma unroll
    for (int e = 0; e < 8; ++e) acc[h][e] = 0.f;

  const float scale = 0.08838834764831845f;  // 1/sqrt(128)
  int iters = CH >> 4;
  bool full = (t0 + CH + 16 <= start_pos);   // margin for 1-stage prefetch
  const size_t kstep = (size_t)16 * NKV * HD;

  if (full) {
    const float* kp = k_cache + ((size_t)(t0 + tl0) * NKV + g) * HD + dbase;
    const float* vp = v_cache + ((size_t)(t0 + tl0) * NKV + g) * HD + dbase;
    f32x4 KA0 = NT4(kp), KB0 = NT4(kp + 4);
    f32x4 VA0 = NT4(vp), VB0 = NT4(vp + 4);
    kp += kstep; vp += kstep;
    for (int i = 0; i < iters; i += 2) {
      f32x4 KA1 = NT4(kp), KB1 = NT4(kp + 4);
      f32x4 VA1 = NT4(vp), VB1 = NT4(vp + 4);
      kp += kstep; vp += kstep;
      __builtin_amdgcn_sched_barrier(0);   // loads above stay above
      STEP(KA0, KB0, VA0, VB0, true);
      KA0 = NT4(kp); KB0 = NT4(kp + 4);
      VA0 = NT4(vp); VB0 = NT4(vp + 4);
      kp += kstep; vp += kstep;
      __builtin_amdgcn_sched_barrier(0);
      STEP(KA1, KB1, VA1, VB1, true);
    }
  } else {
    for (int i = 0; i < iters; ++i) {
      int t = t0 + i * 16 + tl0;
      bool valid = (t < T);
      const float* kp;
      const float* vp;
      if (t < start_pos) {
        kp = k_cache + ((size_t)t * NKV + g) * HD;
        vp = v_cache + ((size_t)t * NKV + g) * HD;
      } else {
        kp = k_new + (size_t)g * HD;   // also safe addr for invalid t
        vp = v_new + (size_t)g * HD;
      }
      f32x4 KA = NT4(kp + dbase), KB = NT4(kp + dbase + 4);
      f32x4 VAx = NT4(vp + dbase), VBx = NT4(vp + dbase + 4);
      STEP(KA, KB, VAx, VBx, valid);
    }
  }

  // ---- combine the 4 groups within each wave (xor 16/32 share d-slice) ----
#pragma unroll
  for (int h = 0; h < 4; ++h) {
    float lh = lsum[h];
    lh += __shfl_xor(lh, 16, 64);
    lh += __shfl_xor(lh, 32, 64);
    lsum[h] = lh;
#pragma unroll
    for (int e = 0; e < 8; ++e) {
      float a = acc[h][e];
      a += __shfl_xor(a, 16, 64);
      a += __shfl_xor(a, 32, 64);
      acc[h][e] = a;
    }
  }
  if (grp == 0) {
#pragma unroll
    for (int h = 0; h < 4; ++h)
#pragma unroll
      for (int e = 0; e < 8; ++e) s_wacc[wvi][h][dbase + e] = acc[h][e];
    if (lig == 0) {
#pragma unroll
      for (int h = 0; h < 4; ++h) s_wl[wvi][h] = lsum[h];
    }
  }
  __syncthreads();
  // ---- combine the 4 waves, write partials ----
  for (int o = tid; o < NREP * HD; o += 256) {
    int h = o >> 7, d = o & (HD - 1);
    float sum = s_wacc[0][h][d] + s_wacc[1][h][d] + s_wacc[2][h][d] +
                s_wacc[3][h][d];
    partial_o[((size_t)(g * NREP + h) * rsplit + split) * HD + d] = sum;
  }
  if (tid < NREP) {
    int hg = g * NREP + tid;
    partial_m[hg * rsplit + split] = 0.f;
    partial_l[hg * rsplit + split] =
        s_wl[0][tid] + s_wl[1][tid] + s_wl[2][tid] + s_wl[3][tid];
  }
}

// ---------------------------------------------------------------------------
// Kernel 3: combine splits. One block (256 threads) per head.
// ---------------------------------------------------------------------------
__global__ __launch_bounds__(256) void combine_kernel(
    const float* __restrict__ partial_m, const float* __restrict__ partial_l,
    const float* __restrict__ partial_o, float* __restrict__ attn_out,
    int rsplit) {
  int h = blockIdx.x;
  int tid = threadIdx.x;
  __shared__ float s_m[SPLITMAX], s_l[SPLITMAX];
  __shared__ float s_acc[2][HD];
  if (tid < rsplit) {
    s_m[tid] = partial_m[h * rsplit + tid];
    s_l[tid] = partial_l[h * rsplit + tid];
  }
  __syncthreads();
  float M = -1e30f;
  for (int s = 0; s < rsplit; ++s) M = fmaxf(M, s_m[s]);
  float L = 0.f;
  for (int s = 0; s < rsplit; ++s) L += s_l[s] * __expf(s_m[s] - M);
  int d = tid & (HD - 1), half = tid >> 7;
  int hn = rsplit >> 1;
  float acc = 0.f;
#pragma unroll 4
  for (int s = half * hn; s < half * hn + hn; ++s)
    acc += __expf(s_m[s] - M) * partial_o[((size_t)h * rsplit + s) * HD + d];
  s_acc[half][d] = acc;
  __syncthreads();
  if (half == 0) attn_out[h * HD + d] = (s_acc[0][d] + s_acc[1][d]) / L;
}

// ---------------------------------------------------------------------------
// Kernel 4: out = attn @ wo.T
// ---------------------------------------------------------------------------
__global__ __launch_bounds__(256) void out_gemv_kernel(
    const float* __restrict__ attn, const float* __restrict__ wo,
    float* __restrict__ out) {
  int row = blockIdx.x * 4 + (threadIdx.x >> 6);
  int lane = threadIdx.x & 63;
  const float4* a4 = (const float4*)attn;
  const float4* w4 = (const float4*)(wo + (size_t)row * DIM);
  float a = 0.f;
#pragma unroll 4
  for (int c = lane; c < DIM / 4; c += 64) {
    float4 av = a4[c];
    float4 wv = w4[c];
    a += av.x * wv.x + av.y * wv.y + av.z * wv.z + av.w * wv.w;
  }
  for (int off = 32; off > 0; off >>= 1) a += __shfl_down(a, off, 64);
  if (lane == 0) out[row] = a;
}

extern "C" void kernel_launch(void* const* d_in, const int* in_sizes, int n_in,
                              void* d_out, int out_size, void* d_ws,
                              size_t ws_size, hipStream_t stream) {
  const float* x       = (const float*)d_in[0];
  const float* fc      = (const float*)d_in[1];
  const float* fs      = (const float*)d_in[2];
  const float* k_cache = (const float*)d_in[3];
  const float* v_cache = (const float*)d_in[4];
  const float* wq      = (const float*)d_in[5];
  const float* wk      = (const float*)d_in[6];
  const float* wv      = (const float*)d_in[7];
  const float* wo      = (const float*)d_in[8];
  float* out = (float*)d_out;

  int start_pos = in_sizes[3] / (NKV * HD);  // cache length
  int T = start_pos + 1;

  // occupancy experiment: rsplit 256 (grid 2048, 8 blocks/CU) w/ ws guard
  int rsplit = SPLITMAX;
  if ((size_t)(10240 + NH * rsplit * (HD + 2)) * 4 > ws_size) rsplit = 128;
  int CH = ((T + rsplit - 1) / rsplit + 15) & ~15;  // 128 for rsplit=256

  float* ws = (float*)d_ws;
  float* q_rope    = ws;                              // 4096
  float* k_new     = ws + 4096;                       // 1024
  float* v_new     = ws + 5120;                       // 1024
  float* attn_out  = ws + 6144;                       // 4096
  float* partial_m = ws + 10240;                      // NH*rsplit
  float* partial_l = partial_m + NH * rsplit;         // NH*rsplit
  float* partial_o = partial_l + NH * rsplit;         // NH*rsplit*HD

  qkv_rope_kernel<<<768, 256, 0, stream>>>(x, fc, fs, wq, wk, wv, q_rope,
                                           k_new, v_new);
  attn_partial_kernel<<<NKV * rsplit, 256, 0, stream>>>(
      q_rope, k_cache, v_cache, k_new, v_new, partial_m, partial_l, partial_o,
      start_pos, T, CH, rsplit);
  combine_kernel<<<NH, 256, 0, stream>>>(partial_m, partial_l, partial_o,
                                         attn_out, rsplit);
  out_gemv_kernel<<<1024, 256, 0, stream>>>(attn_out, wo, out);
}

// Round 17
// 124.432 us; speedup vs baseline: 3.0929x; 3.0929x over previous
//
#include <hip/hip_runtime.h>
#include <math.h>

#define DIM 4096
#define NH 32
#define NKV 8
#define HD 128
#define NREP 4
#define SPLITMAX 256

typedef float f32x4 __attribute__((ext_vector_type(4)));

// ---------------------------------------------------------------------------
// Kernel 1: q/k/v GEMV + fused RoPE.
// ---------------------------------------------------------------------------
__global__ __launch_bounds__(256) void qkv_rope_kernel(
    const float* __restrict__ x, const float* __restrict__ fc,
    const float* __restrict__ fs, const float* __restrict__ wq,
    const float* __restrict__ wk, const float* __restrict__ wv,
    float* __restrict__ q_rope, float* __restrict__ k_new,
    float* __restrict__ v_new) {
  int wave = blockIdx.x * 4 + (threadIdx.x >> 6);
  int lane = threadIdx.x & 63;
  const float* W;
  float* dst;
  int r0;
  bool rope;
  if (wave < 2048) {            // q: 4096 rows
    W = wq; dst = q_rope; r0 = wave * 2; rope = true;
  } else if (wave < 2560) {     // k: 1024 rows
    W = wk; dst = k_new; r0 = (wave - 2048) * 2; rope = true;
  } else {                      // v: 1024 rows
    W = wv; dst = v_new; r0 = (wave - 2560) * 2; rope = false;
  }
  const float4* x4 = (const float4*)x;
  const float4* w0 = (const float4*)(W + (size_t)r0 * DIM);
  const float4* w1 = (const float4*)(W + (size_t)(r0 + 1) * DIM);
  float a0 = 0.f, a1 = 0.f;
#pragma unroll 4
  for (int c = lane; c < DIM / 4; c += 64) {
    float4 xv = x4[c];
    float4 u = w0[c];
    float4 v = w1[c];
    a0 += xv.x * u.x + xv.y * u.y + xv.z * u.z + xv.w * u.w;
    a1 += xv.x * v.x + xv.y * v.y + xv.z * v.z + xv.w * v.w;
  }
  for (int off = 32; off > 0; off >>= 1) {
    a0 += __shfl_down(a0, off, 64);
    a1 += __shfl_down(a1, off, 64);
  }
  if (lane == 0) {
    if (rope) {
      int j = (r0 & (HD - 1)) >> 1;
      float c = fc[j], s = fs[j];
      dst[r0]     = a0 * c - a1 * s;
      dst[r0 + 1] = a0 * s + a1 * c;
    } else {
      dst[r0]     = a0;
      dst[r0 + 1] = a1;
    }
  }
}

#define LD4(p) (*(const float4*)(p))
// non-temporal load: bypass LLC allocation for the streaming K/V cache
// (R15: 96.5 -> 92.8 us; KV consumption ~3.1 -> ~4.3 TB/s).
#define NT4(p) (__builtin_nontemporal_load((const f32x4*)(p)))

#define DOT4(sv, h)                                                         \
  sv = A.x * qf[h][0] + A.y * qf[h][1] + A.z * qf[h][2] + A.w * qf[h][3] +  \
       B.x * qf[h][4] + B.y * qf[h][5] + B.z * qf[h][6] + B.w * qf[h][7];

#define PV8(h, e)                                                           \
  acc[h][0] += (e)*VA.x; acc[h][1] += (e)*VA.y;                             \
  acc[h][2] += (e)*VA.z; acc[h][3] += (e)*VA.w;                             \
  acc[h][4] += (e)*VB.x; acc[h][5] += (e)*VB.y;                             \
  acc[h][6] += (e)*VB.z; acc[h][7] += (e)*VB.w;

// One position-step: K-dots for 4 heads, 5-shuffle transposed reduce,
// 3-shuffle broadcast, exp (fixed m=0 reference), PV accumulate.
#define STEP(KA_, KB_, VA_, VB_, VALID)                                     \
  {                                                                         \
    auto A = KA_; auto B = KB_;                                             \
    float s0, s1, s2, s3;                                                   \
    DOT4(s0, 0); DOT4(s1, 1); DOT4(s2, 2); DOT4(s3, 3);                     \
    float pp = hi8 ? s2 : s0, pq = hi8 ? s0 : s2;                           \
    pp += __shfl_xor(pq, 8, 64);                                            \
    float rr = hi8 ? s3 : s1, rs = hi8 ? s1 : s3;                           \
    rr += __shfl_xor(rs, 8, 64);                                            \
    float u = hi4 ? rr : pp, uvx = hi4 ? pp : rr;                           \
    u += __shfl_xor(uvx, 4, 64);                                            \
    u += __shfl_xor(u, 1, 64);                                              \
    u += __shfl_xor(u, 2, 64);                                              \
    float u4 = __shfl_xor(u, 4, 64);                                        \
    float u8 = __shfl_xor(u, 8, 64);                                        \
    float u12 = __shfl_xor(u4, 8, 64);                                      \
    float q0 = hi4 ? u4 : u,   q1 = hi4 ? u : u4;                           \
    float q2 = hi4 ? u12 : u8, q3 = hi4 ? u8 : u12;                         \
    float w0 = hi8 ? q2 : q0, w1 = hi8 ? q3 : q1;                           \
    float w2 = hi8 ? q0 : q2, w3 = hi8 ? q1 : q3;                           \
    float e0 = __expf((VALID) ? w0 * scale : -1e30f);                       \
    float e1 = __expf((VALID) ? w1 * scale : -1e30f);                       \
    float e2 = __expf((VALID) ? w2 * scale : -1e30f);                       \
    float e3 = __expf((VALID) ? w3 * scale : -1e30f);                       \
    lsum[0] += e0; lsum[1] += e1; lsum[2] += e2; lsum[3] += e3;             \
    auto VA = VA_; auto VB = VB_;                                           \
    PV8(0, e0) PV8(1, e1) PV8(2, e2) PV8(3, e3)                             \
  }

// ---------------------------------------------------------------------------
// Kernel 2: flash-decode partials (m=0 reference, validated R4-R15).
// R15 vehicle (nt loads, launch_bounds(256,4) -> VGPR 64, no spill).
// R17: rsplit 256 (grid 2048) — more blocks/CU via natural residency
// (VGPR 64 permits 8 waves/SIMD), NOT via regalloc forcing (R16 spilled).
// ---------------------------------------------------------------------------
__global__ __launch_bounds__(256, 4) void attn_partial_kernel(
    const float* __restrict__ q_rope, const float* __restrict__ k_cache,
    const float* __restrict__ v_cache, const float* __restrict__ k_new,
    const float* __restrict__ v_new, float* __restrict__ partial_m,
    float* __restrict__ partial_l, float* __restrict__ partial_o,
    int start_pos, int T, int CH, int rsplit) {
  int g = blockIdx.x % NKV;
  int split = blockIdx.x / NKV;
  int t0 = split * CH;
  int tid = threadIdx.x;
  int wvi = tid >> 6;
  int lane = tid & 63;
  int grp = lane >> 4;
  int lig = lane & 15;
  int tl0 = wvi * 4 + grp;
  int dbase = lig * 8;
  bool hi8 = (lig & 8) != 0, hi4 = (lig & 4) != 0;

  __shared__ float s_wacc[4][4][HD];
  __shared__ float s_wl[4][4];

  float qf[4][8];
#pragma unroll
  for (int h = 0; h < 4; ++h)
#pragma unroll
    for (int e = 0; e < 8; ++e)
      qf[h][e] = q_rope[(g * NREP + h) * HD + dbase + e];

  float lsum[4] = {0.f, 0.f, 0.f, 0.f};
  float acc[4][8];
#pragma unroll
  for (int h = 0; h < 4; ++h)
#pragma unroll
    for (int e = 0; e < 8; ++e) acc[h][e] = 0.f;

  const float scale = 0.08838834764831845f;  // 1/sqrt(128)
  int iters = CH >> 4;
  bool full = (t0 + CH + 16 <= start_pos);   // margin for 1-stage prefetch
  const size_t kstep = (size_t)16 * NKV * HD;

  if (full) {
    const float* kp = k_cache + ((size_t)(t0 + tl0) * NKV + g) * HD + dbase;
    const float* vp = v_cache + ((size_t)(t0 + tl0) * NKV + g) * HD + dbase;
    f32x4 KA0 = NT4(kp), KB0 = NT4(kp + 4);
    f32x4 VA0 = NT4(vp), VB0 = NT4(vp + 4);
    kp += kstep; vp += kstep;
    for (int i = 0; i < iters; i += 2) {
      f32x4 KA1 = NT4(kp), KB1 = NT4(kp + 4);
      f32x4 VA1 = NT4(vp), VB1 = NT4(vp + 4);
      kp += kstep; vp += kstep;
      __builtin_amdgcn_sched_barrier(0);   // loads above stay above
      STEP(KA0, KB0, VA0, VB0, true);
      KA0 = NT4(kp); KB0 = NT4(kp + 4);
      VA0 = NT4(vp); VB0 = NT4(vp + 4);
      kp += kstep; vp += kstep;
      __builtin_amdgcn_sched_barrier(0);
      STEP(KA1, KB1, VA1, VB1, true);
    }
  } else {
    for (int i = 0; i < iters; ++i) {
      int t = t0 + i * 16 + tl0;
      bool valid = (t < T);
      const float* kp;
      const float* vp;
      if (t < start_pos) {
        kp = k_cache + ((size_t)t * NKV + g) * HD;
        vp = v_cache + ((size_t)t * NKV + g) * HD;
      } else {
        kp = k_new + (size_t)g * HD;   // also safe addr for invalid t
        vp = v_new + (size_t)g * HD;
      }
      f32x4 KA = NT4(kp + dbase), KB = NT4(kp + dbase + 4);
      f32x4 VAx = NT4(vp + dbase), VBx = NT4(vp + dbase + 4);
      STEP(KA, KB, VAx, VBx, valid);
    }
  }

  // ---- combine the 4 groups within each wave (xor 16/32 share d-slice) ----
#pragma unroll
  for (int h = 0; h < 4; ++h) {
    float lh = lsum[h];
    lh += __shfl_xor(lh, 16, 64);
    lh += __shfl_xor(lh, 32, 64);
    lsum[h] = lh;
#pragma unroll
    for (int e = 0; e < 8; ++e) {
      float a = acc[h][e];
      a += __shfl_xor(a, 16, 64);
      a += __shfl_xor(a, 32, 64);
      acc[h][e] = a;
    }
  }
  if (grp == 0) {
#pragma unroll
    for (int h = 0; h < 4; ++h)
#pragma unroll
      for (int e = 0; e < 8; ++e) s_wacc[wvi][h][dbase + e] = acc[h][e];
    if (lig == 0) {
#pragma unroll
      for (int h = 0; h < 4; ++h) s_wl[wvi][h] = lsum[h];
    }
  }
  __syncthreads();
  // ---- combine the 4 waves, write partials ----
  for (int o = tid; o < NREP * HD; o += 256) {
    int h = o >> 7, d = o & (HD - 1);
    float sum = s_wacc[0][h][d] + s_wacc[1][h][d] + s_wacc[2][h][d] +
                s_wacc[3][h][d];
    partial_o[((size_t)(g * NREP + h) * rsplit + split) * HD + d] = sum;
  }
  if (tid < NREP) {
    int hg = g * NREP + tid;
    partial_m[hg * rsplit + split] = 0.f;
    partial_l[hg * rsplit + split] =
        s_wl[0][tid] + s_wl[1][tid] + s_wl[2][tid] + s_wl[3][tid];
  }
}

// ---------------------------------------------------------------------------
// Kernel 3: combine splits. One block (256 threads) per head.
// ---------------------------------------------------------------------------
__global__ __launch_bounds__(256) void combine_kernel(
    const float* __restrict__ partial_m, const float* __restrict__ partial_l,
    const float* __restrict__ partial_o, float* __restrict__ attn_out,
    int rsplit) {
  int h = blockIdx.x;
  int tid = threadIdx.x;
  __shared__ float s_m[SPLITMAX], s_l[SPLITMAX];
  __shared__ float s_acc[2][HD];
  if (tid < rsplit) {
    s_m[tid] = partial_m[h * rsplit + tid];
    s_l[tid] = partial_l[h * rsplit + tid];
  }
  __syncthreads();
  float M = -1e30f;
  for (int s = 0; s < rsplit; ++s) M = fmaxf(M, s_m[s]);
  float L = 0.f;
  for (int s = 0; s < rsplit; ++s) L += s_l[s] * __expf(s_m[s] - M);
  int d = tid & (HD - 1), half = tid >> 7;
  int hn = rsplit >> 1;
  float acc = 0.f;
#pragma unroll 4
  for (int s = half * hn; s < half * hn + hn; ++s)
    acc += __expf(s_m[s] - M) * partial_o[((size_t)h * rsplit + s) * HD + d];
  s_acc[half][d] = acc;
  __syncthreads();
  if (half == 0) attn_out[h * HD + d] = (s_acc[0][d] + s_acc[1][d]) / L;
}

// ---------------------------------------------------------------------------
// Kernel 4: out = attn @ wo.T
// ---------------------------------------------------------------------------
__global__ __launch_bounds__(256) void out_gemv_kernel(
    const float* __restrict__ attn, const float* __restrict__ wo,
    float* __restrict__ out) {
  int row = blockIdx.x * 4 + (threadIdx.x >> 6);
  int lane = threadIdx.x & 63;
  const float4* a4 = (const float4*)attn;
  const float4* w4 = (const float4*)(wo + (size_t)row * DIM);
  float a = 0.f;
#pragma unroll 4
  for (int c = lane; c < DIM / 4; c += 64) {
    float4 av = a4[c];
    float4 wv = w4[c];
    a += av.x * wv.x + av.y * wv.y + av.z * wv.z + av.w * wv.w;
  }
  for (int off = 32; off > 0; off >>= 1) a += __shfl_down(a, off, 64);
  if (lane == 0) out[row] = a;
}

extern "C" void kernel_launch(void* const* d_in, const int* in_sizes, int n_in,
                              void* d_out, int out_size, void* d_ws,
                              size_t ws_size, hipStream_t stream) {
  const float* x       = (const float*)d_in[0];
  const float* fc      = (const float*)d_in[1];
  const float* fs      = (const float*)d_in[2];
  const float* k_cache = (const float*)d_in[3];
  const float* v_cache = (const float*)d_in[4];
  const float* wq      = (const float*)d_in[5];
  const float* wk      = (const float*)d_in[6];
  const float* wv      = (const float*)d_in[7];
  const float* wo      = (const float*)d_in[8];
  float* out = (float*)d_out;

  int start_pos = in_sizes[3] / (NKV * HD);  // cache length
  int T = start_pos + 1;

  // grid 2048 via rsplit 256 (natural residency, no regalloc forcing)
  int rsplit = SPLITMAX;
  if ((size_t)(10240 + NH * rsplit * (HD + 2)) * 4 > ws_size) rsplit = 128;
  int CH = ((T + rsplit - 1) / rsplit + 15) & ~15;  // 128 for rsplit=256

  float* ws = (float*)d_ws;
  float* q_rope    = ws;                              // 4096
  float* k_new     = ws + 4096;                       // 1024
  float* v_new     = ws + 5120;                       // 1024
  float* attn_out  = ws + 6144;                       // 4096
  float* partial_m = ws + 10240;                      // NH*rsplit
  float* partial_l = partial_m + NH * rsplit;         // NH*rsplit
  float* partial_o = partial_l + NH * rsplit;         // NH*rsplit*HD

  qkv_rope_kernel<<<768, 256, 0, stream>>>(x, fc, fs, wq, wk, wv, q_rope,
                                           k_new, v_new);
  attn_partial_kernel<<<NKV * rsplit, 256, 0, stream>>>(
      q_rope, k_cache, v_cache, k_new, v_new, partial_m, partial_l, partial_o,
      start_pos, T, CH, rsplit);
  combine_kernel<<<NH, 256, 0, stream>>>(partial_m, partial_l, partial_o,
                                         attn_out, rsplit);
  out_gemv_kernel<<<1024, 256, 0, stream>>>(attn_out, wo, out);
}

// Round 18
// 92.289 us; speedup vs baseline: 4.1701x; 1.3483x over previous
//
#include <hip/hip_runtime.h>
#include <math.h>

#define DIM 4096
#define NH 32
#define NKV 8
#define HD 128
#define NREP 4
#define RSPLIT 128

typedef float f32x4 __attribute__((ext_vector_type(4)));

// ---------------------------------------------------------------------------
// Kernel 1: q/k/v GEMV + fused RoPE. Block 0 additionally zeroes the
// attention accumulator (attn_raw[4096] | L_raw[32]) — stream order
// guarantees completion before attn_partial_kernel's atomics.
// ---------------------------------------------------------------------------
__global__ __launch_bounds__(256) void qkv_rope_kernel(
    const float* __restrict__ x, const float* __restrict__ fc,
    const float* __restrict__ fs, const float* __restrict__ wq,
    const float* __restrict__ wk, const float* __restrict__ wv,
    float* __restrict__ q_rope, float* __restrict__ k_new,
    float* __restrict__ v_new, float* __restrict__ attn_raw) {
  if (blockIdx.x == 0) {
    for (int i = threadIdx.x; i < NH * HD + NH; i += 256) attn_raw[i] = 0.f;
  }
  int wave = blockIdx.x * 4 + (threadIdx.x >> 6);
  int lane = threadIdx.x & 63;
  const float* W;
  float* dst;
  int r0;
  bool rope;
  if (wave < 2048) {            // q: 4096 rows
    W = wq; dst = q_rope; r0 = wave * 2; rope = true;
  } else if (wave < 2560) {     // k: 1024 rows
    W = wk; dst = k_new; r0 = (wave - 2048) * 2; rope = true;
  } else {                      // v: 1024 rows
    W = wv; dst = v_new; r0 = (wave - 2560) * 2; rope = false;
  }
  const float4* x4 = (const float4*)x;
  const float4* w0 = (const float4*)(W + (size_t)r0 * DIM);
  const float4* w1 = (const float4*)(W + (size_t)(r0 + 1) * DIM);
  float a0 = 0.f, a1 = 0.f;
#pragma unroll 4
  for (int c = lane; c < DIM / 4; c += 64) {
    float4 xv = x4[c];
    float4 u = w0[c];
    float4 v = w1[c];
    a0 += xv.x * u.x + xv.y * u.y + xv.z * u.z + xv.w * u.w;
    a1 += xv.x * v.x + xv.y * v.y + xv.z * v.z + xv.w * v.w;
  }
  for (int off = 32; off > 0; off >>= 1) {
    a0 += __shfl_down(a0, off, 64);
    a1 += __shfl_down(a1, off, 64);
  }
  if (lane == 0) {
    if (rope) {
      int j = (r0 & (HD - 1)) >> 1;
      float c = fc[j], s = fs[j];
      dst[r0]     = a0 * c - a1 * s;
      dst[r0 + 1] = a0 * s + a1 * c;
    } else {
      dst[r0]     = a0;
      dst[r0 + 1] = a1;
    }
  }
}

#define LD4(p) (*(const float4*)(p))
// non-temporal load: bypass LLC allocation for the streaming K/V cache
// (R15: 96.5 -> 92.8 us; KV consumption ~3.1 -> ~4.3 TB/s).
#define NT4(p) (__builtin_nontemporal_load((const f32x4*)(p)))

#define DOT4(sv, h)                                                         \
  sv = A.x * qf[h][0] + A.y * qf[h][1] + A.z * qf[h][2] + A.w * qf[h][3] +  \
       B.x * qf[h][4] + B.y * qf[h][5] + B.z * qf[h][6] + B.w * qf[h][7];

#define PV8(h, e)                                                           \
  acc[h][0] += (e)*VA.x; acc[h][1] += (e)*VA.y;                             \
  acc[h][2] += (e)*VA.z; acc[h][3] += (e)*VA.w;                             \
  acc[h][4] += (e)*VB.x; acc[h][5] += (e)*VB.y;                             \
  acc[h][6] += (e)*VB.z; acc[h][7] += (e)*VB.w;

// One position-step: K-dots for 4 heads, 5-shuffle transposed reduce,
// 3-shuffle broadcast, exp (fixed m=0 reference), PV accumulate.
#define STEP(KA_, KB_, VA_, VB_, VALID)                                     \
  {                                                                         \
    auto A = KA_; auto B = KB_;                                             \
    float s0, s1, s2, s3;                                                   \
    DOT4(s0, 0); DOT4(s1, 1); DOT4(s2, 2); DOT4(s3, 3);                     \
    float pp = hi8 ? s2 : s0, pq = hi8 ? s0 : s2;                           \
    pp += __shfl_xor(pq, 8, 64);                                            \
    float rr = hi8 ? s3 : s1, rs = hi8 ? s1 : s3;                           \
    rr += __shfl_xor(rs, 8, 64);                                            \
    float u = hi4 ? rr : pp, uvx = hi4 ? pp : rr;                           \
    u += __shfl_xor(uvx, 4, 64);                                            \
    u += __shfl_xor(u, 1, 64);                                              \
    u += __shfl_xor(u, 2, 64);                                              \
    float u4 = __shfl_xor(u, 4, 64);                                        \
    float u8 = __shfl_xor(u, 8, 64);                                        \
    float u12 = __shfl_xor(u4, 8, 64);                                      \
    float q0 = hi4 ? u4 : u,   q1 = hi4 ? u : u4;                           \
    float q2 = hi4 ? u12 : u8, q3 = hi4 ? u8 : u12;                         \
    float w0 = hi8 ? q2 : q0, w1 = hi8 ? q3 : q1;                           \
    float w2 = hi8 ? q0 : q2, w3 = hi8 ? q1 : q3;                           \
    float e0 = __expf((VALID) ? w0 * scale : -1e30f);                       \
    float e1 = __expf((VALID) ? w1 * scale : -1e30f);                       \
    float e2 = __expf((VALID) ? w2 * scale : -1e30f);                       \
    float e3 = __expf((VALID) ? w3 * scale : -1e30f);                       \
    lsum[0] += e0; lsum[1] += e1; lsum[2] += e2; lsum[3] += e3;             \
    auto VA = VA_; auto VB = VB_;                                           \
    PV8(0, e0) PV8(1, e1) PV8(2, e2) PV8(3, e3)                             \
  }

// ---------------------------------------------------------------------------
// Kernel 2: flash-decode partials (m=0 reference, validated R4-R17).
// EXACT R15 vehicle (nt loads, launch_bounds(256,4), rsplit 128, CH 256 —
// best measured: 92.8us; R16/R17 showed both forced-occupancy and more
// blocks regress). Epilogue now atomicAdds straight into attn_raw/L_raw
// (m=0 -> partials are plain sums), removing the combine kernel.
// ---------------------------------------------------------------------------
__global__ __launch_bounds__(256, 4) void attn_partial_kernel(
    const float* __restrict__ q_rope, const float* __restrict__ k_cache,
    const float* __restrict__ v_cache, const float* __restrict__ k_new,
    const float* __restrict__ v_new, float* __restrict__ attn_raw,
    float* __restrict__ L_raw, int start_pos, int T, int CH) {
  int g = blockIdx.x % NKV;
  int split = blockIdx.x / NKV;
  int t0 = split * CH;
  int tid = threadIdx.x;
  int wvi = tid >> 6;
  int lane = tid & 63;
  int grp = lane >> 4;
  int lig = lane & 15;
  int tl0 = wvi * 4 + grp;
  int dbase = lig * 8;
  bool hi8 = (lig & 8) != 0, hi4 = (lig & 4) != 0;

  __shared__ float s_wacc[4][4][HD];
  __shared__ float s_wl[4][4];

  float qf[4][8];
#pragma unroll
  for (int h = 0; h < 4; ++h)
#pragma unroll
    for (int e = 0; e < 8; ++e)
      qf[h][e] = q_rope[(g * NREP + h) * HD + dbase + e];

  float lsum[4] = {0.f, 0.f, 0.f, 0.f};
  float acc[4][8];
#pragma unroll
  for (int h = 0; h < 4; ++h)
#pragma unroll
    for (int e = 0; e < 8; ++e) acc[h][e] = 0.f;

  const float scale = 0.08838834764831845f;  // 1/sqrt(128)
  int iters = CH >> 4;
  bool full = (t0 + CH + 16 <= start_pos);   // margin for 1-stage prefetch
  const size_t kstep = (size_t)16 * NKV * HD;

  if (full) {
    const float* kp = k_cache + ((size_t)(t0 + tl0) * NKV + g) * HD + dbase;
    const float* vp = v_cache + ((size_t)(t0 + tl0) * NKV + g) * HD + dbase;
    f32x4 KA0 = NT4(kp), KB0 = NT4(kp + 4);
    f32x4 VA0 = NT4(vp), VB0 = NT4(vp + 4);
    kp += kstep; vp += kstep;
    for (int i = 0; i < iters; i += 2) {
      f32x4 KA1 = NT4(kp), KB1 = NT4(kp + 4);
      f32x4 VA1 = NT4(vp), VB1 = NT4(vp + 4);
      kp += kstep; vp += kstep;
      __builtin_amdgcn_sched_barrier(0);   // loads above stay above
      STEP(KA0, KB0, VA0, VB0, true);
      KA0 = NT4(kp); KB0 = NT4(kp + 4);
      VA0 = NT4(vp); VB0 = NT4(vp + 4);
      kp += kstep; vp += kstep;
      __builtin_amdgcn_sched_barrier(0);
      STEP(KA1, KB1, VA1, VB1, true);
    }
  } else {
    for (int i = 0; i < iters; ++i) {
      int t = t0 + i * 16 + tl0;
      bool valid = (t < T);
      const float* kp;
      const float* vp;
      if (t < start_pos) {
        kp = k_cache + ((size_t)t * NKV + g) * HD;
        vp = v_cache + ((size_t)t * NKV + g) * HD;
      } else {
        kp = k_new + (size_t)g * HD;   // also safe addr for invalid t
        vp = v_new + (size_t)g * HD;
      }
      f32x4 KA = NT4(kp + dbase), KB = NT4(kp + dbase + 4);
      f32x4 VAx = NT4(vp + dbase), VBx = NT4(vp + dbase + 4);
      STEP(KA, KB, VAx, VBx, valid);
    }
  }

  // ---- combine the 4 groups within each wave (xor 16/32 share d-slice) ----
#pragma unroll
  for (int h = 0; h < 4; ++h) {
    float lh = lsum[h];
    lh += __shfl_xor(lh, 16, 64);
    lh += __shfl_xor(lh, 32, 64);
    lsum[h] = lh;
#pragma unroll
    for (int e = 0; e < 8; ++e) {
      float a = acc[h][e];
      a += __shfl_xor(a, 16, 64);
      a += __shfl_xor(a, 32, 64);
      acc[h][e] = a;
    }
  }
  if (grp == 0) {
#pragma unroll
    for (int h = 0; h < 4; ++h)
#pragma unroll
      for (int e = 0; e < 8; ++e) s_wacc[wvi][h][dbase + e] = acc[h][e];
    if (lig == 0) {
#pragma unroll
      for (int h = 0; h < 4; ++h) s_wl[wvi][h] = lsum[h];
    }
  }
  __syncthreads();
  // ---- combine the 4 waves, accumulate into global (m=0 -> plain sums) ----
  for (int o = tid; o < NREP * HD; o += 256) {
    int h = o >> 7, d = o & (HD - 1);
    float sum = s_wacc[0][h][d] + s_wacc[1][h][d] + s_wacc[2][h][d] +
                s_wacc[3][h][d];
    atomicAdd(&attn_raw[(g * NREP + h) * HD + d], sum);
  }
  if (tid < NREP) {
    atomicAdd(&L_raw[g * NREP + tid],
              s_wl[0][tid] + s_wl[1][tid] + s_wl[2][tid] + s_wl[3][tid]);
  }
}

// ---------------------------------------------------------------------------
// Kernel 3: out = (attn_raw / L) @ wo.T — normalization folded in via a
// 32-entry invL LDS table.
// ---------------------------------------------------------------------------
__global__ __launch_bounds__(256) void out_gemv_kernel(
    const float* __restrict__ attn_raw, const float* __restrict__ L_raw,
    const float* __restrict__ wo, float* __restrict__ out) {
  __shared__ float s_invL[NH];
  if (threadIdx.x < NH) s_invL[threadIdx.x] = 1.f / L_raw[threadIdx.x];
  __syncthreads();
  int row = blockIdx.x * 4 + (threadIdx.x >> 6);
  int lane = threadIdx.x & 63;
  const float4* a4 = (const float4*)attn_raw;
  const float4* w4 = (const float4*)(wo + (size_t)row * DIM);
  float a = 0.f;
#pragma unroll 4
  for (int c = lane; c < DIM / 4; c += 64) {
    float4 av = a4[c];
    float4 wv = w4[c];
    float il = s_invL[c >> 5];   // head = float4-index / 32
    a += (av.x * wv.x + av.y * wv.y + av.z * wv.z + av.w * wv.w) * il;
  }
  for (int off = 32; off > 0; off >>= 1) a += __shfl_down(a, off, 64);
  if (lane == 0) out[row] = a;
}

extern "C" void kernel_launch(void* const* d_in, const int* in_sizes, int n_in,
                              void* d_out, int out_size, void* d_ws,
                              size_t ws_size, hipStream_t stream) {
  const float* x       = (const float*)d_in[0];
  const float* fc      = (const float*)d_in[1];
  const float* fs      = (const float*)d_in[2];
  const float* k_cache = (const float*)d_in[3];
  const float* v_cache = (const float*)d_in[4];
  const float* wq      = (const float*)d_in[5];
  const float* wk      = (const float*)d_in[6];
  const float* wv      = (const float*)d_in[7];
  const float* wo      = (const float*)d_in[8];
  float* out = (float*)d_out;

  int start_pos = in_sizes[3] / (NKV * HD);  // cache length
  int T = start_pos + 1;
  int CH = ((T + RSPLIT - 1) / RSPLIT + 15) & ~15;  // 256 for T=32768

  float* ws = (float*)d_ws;
  float* q_rope   = ws;            // 4096
  float* k_new    = ws + 4096;     // 1024
  float* v_new    = ws + 5120;     // 1024
  float* attn_raw = ws + 6144;     // 4096 (+32 L_raw, zeroed by qkv block 0)
  float* L_raw    = attn_raw + NH * HD;  // 32

  qkv_rope_kernel<<<768, 256, 0, stream>>>(x, fc, fs, wq, wk, wv, q_rope,
                                           k_new, v_new, attn_raw);
  attn_partial_kernel<<<NKV * RSPLIT, 256, 0, stream>>>(
      q_rope, k_cache, v_cache, k_new, v_new, attn_raw, L_raw,
      start_pos, T, CH);
  out_gemv_kernel<<<1024, 256, 0, stream>>>(attn_raw, L_raw, wo, out);
}

// Round 19
// 87.267 us; speedup vs baseline: 4.4100x; 1.0575x over previous
//
#include <hip/hip_runtime.h>
#include <math.h>

#define DIM 4096
#define NH 32
#define NKV 8
#define HD 128
#define NREP 4
#define NSPLIT 256   // splits per g-pair; grid = 4 * 256 = 1024

typedef float f32x4 __attribute__((ext_vector_type(4)));

// ---------------------------------------------------------------------------
// Kernel 1: q/k/v GEMV + fused RoPE. Block 0 zeroes attn accumulator.
// ---------------------------------------------------------------------------
__global__ __launch_bounds__(256) void qkv_rope_kernel(
    const float* __restrict__ x, const float* __restrict__ fc,
    const float* __restrict__ fs, const float* __restrict__ wq,
    const float* __restrict__ wk, const float* __restrict__ wv,
    float* __restrict__ q_rope, float* __restrict__ k_new,
    float* __restrict__ v_new, float* __restrict__ attn_raw) {
  if (blockIdx.x == 0) {
    for (int i = threadIdx.x; i < NH * HD + NH; i += 256) attn_raw[i] = 0.f;
  }
  int wave = blockIdx.x * 4 + (threadIdx.x >> 6);
  int lane = threadIdx.x & 63;
  const float* W;
  float* dst;
  int r0;
  bool rope;
  if (wave < 2048) {            // q: 4096 rows
    W = wq; dst = q_rope; r0 = wave * 2; rope = true;
  } else if (wave < 2560) {     // k: 1024 rows
    W = wk; dst = k_new; r0 = (wave - 2048) * 2; rope = true;
  } else {                      // v: 1024 rows
    W = wv; dst = v_new; r0 = (wave - 2560) * 2; rope = false;
  }
  const float4* x4 = (const float4*)x;
  const float4* w0 = (const float4*)(W + (size_t)r0 * DIM);
  const float4* w1 = (const float4*)(W + (size_t)(r0 + 1) * DIM);
  float a0 = 0.f, a1 = 0.f;
#pragma unroll 4
  for (int c = lane; c < DIM / 4; c += 64) {
    float4 xv = x4[c];
    float4 u = w0[c];
    float4 v = w1[c];
    a0 += xv.x * u.x + xv.y * u.y + xv.z * u.z + xv.w * u.w;
    a1 += xv.x * v.x + xv.y * v.y + xv.z * v.z + xv.w * v.w;
  }
  for (int off = 32; off > 0; off >>= 1) {
    a0 += __shfl_down(a0, off, 64);
    a1 += __shfl_down(a1, off, 64);
  }
  if (lane == 0) {
    if (rope) {
      int j = (r0 & (HD - 1)) >> 1;
      float c = fc[j], s = fs[j];
      dst[r0]     = a0 * c - a1 * s;
      dst[r0 + 1] = a0 * s + a1 * c;
    } else {
      dst[r0]     = a0;
      dst[r0 + 1] = a1;
    }
  }
}

#define LD4(p) (*(const float4*)(p))
// non-temporal: bypass LLC allocation (R15: 96.5 -> 92.8 us)
#define NT4(p) (__builtin_nontemporal_load((const f32x4*)(p)))

#define DOT4(sv, h)                                                         \
  sv = A.x * qf[h][0] + A.y * qf[h][1] + A.z * qf[h][2] + A.w * qf[h][3] +  \
       B.x * qf[h][4] + B.y * qf[h][5] + B.z * qf[h][6] + B.w * qf[h][7];

#define PV8(h, e)                                                           \
  acc[h][0] += (e)*VA.x; acc[h][1] += (e)*VA.y;                             \
  acc[h][2] += (e)*VA.z; acc[h][3] += (e)*VA.w;                             \
  acc[h][4] += (e)*VB.x; acc[h][5] += (e)*VB.y;                             \
  acc[h][6] += (e)*VB.z; acc[h][7] += (e)*VB.w;

// One position-step (per 16-lane group): K-dots for this g's 4 heads,
// 5-shuffle intra-group reduce, 3-shuffle broadcast, exp (m=0 reference),
// PV accumulate. Intra-group only — safe for the 2-g remap.
#define STEP(KA_, KB_, VA_, VB_, VALID)                                     \
  {                                                                         \
    auto A = KA_; auto B = KB_;                                             \
    float s0, s1, s2, s3;                                                   \
    DOT4(s0, 0); DOT4(s1, 1); DOT4(s2, 2); DOT4(s3, 3);                     \
    float pp = hi8 ? s2 : s0, pq = hi8 ? s0 : s2;                           \
    pp += __shfl_xor(pq, 8, 64);                                            \
    float rr = hi8 ? s3 : s1, rs = hi8 ? s1 : s3;                           \
    rr += __shfl_xor(rs, 8, 64);                                            \
    float u = hi4 ? rr : pp, uvx = hi4 ? pp : rr;                           \
    u += __shfl_xor(uvx, 4, 64);                                            \
    u += __shfl_xor(u, 1, 64);                                              \
    u += __shfl_xor(u, 2, 64);                                              \
    float u4 = __shfl_xor(u, 4, 64);                                        \
    float u8 = __shfl_xor(u, 8, 64);                                        \
    float u12 = __shfl_xor(u4, 8, 64);                                      \
    float q0 = hi4 ? u4 : u,   q1 = hi4 ? u : u4;                           \
    float q2 = hi4 ? u12 : u8, q3 = hi4 ? u8 : u12;                         \
    float w0 = hi8 ? q2 : q0, w1 = hi8 ? q3 : q1;                           \
    float w2 = hi8 ? q0 : q2, w3 = hi8 ? q1 : q3;                           \
    float e0 = __expf((VALID) ? w0 * scale : -1e30f);                       \
    float e1 = __expf((VALID) ? w1 * scale : -1e30f);                       \
    float e2 = __expf((VALID) ? w2 * scale : -1e30f);                       \
    float e3 = __expf((VALID) ? w3 * scale : -1e30f);                       \
    lsum[0] += e0; lsum[1] += e1; lsum[2] += e2; lsum[3] += e3;             \
    auto VA = VA_; auto VB = VB_;                                           \
    PV8(0, e0) PV8(1, e1) PV8(2, e2) PV8(3, e3)                             \
  }

// ---------------------------------------------------------------------------
// Kernel 2: flash-decode partials (m=0 reference, validated R4-R18).
// R19: block = (g-PAIR, split). Wave's 4 groups map to 2 positions x 2
// adjacent kv-heads -> each wave load covers 2 x 1KB CONTIGUOUS chunks
// (vs 4 x 512B) for double DRAM page density. Same VGPR budget: lane
// still owns 4 heads (of its g) x 8 dims.
// ---------------------------------------------------------------------------
__global__ __launch_bounds__(256, 4) void attn_partial_kernel(
    const float* __restrict__ q_rope, const float* __restrict__ k_cache,
    const float* __restrict__ v_cache, const float* __restrict__ k_new,
    const float* __restrict__ v_new, float* __restrict__ attn_raw,
    float* __restrict__ L_raw, int start_pos, int T, int CH) {
  int g0 = (blockIdx.x & 3) * 2;    // g-pair base
  int split = blockIdx.x >> 2;
  int t0 = split * CH;
  int tid = threadIdx.x;
  int wvi = tid >> 6;
  int lane = tid & 63;
  int grp = lane >> 4;
  int lig = lane & 15;
  int gsel = grp & 1;               // which g of the pair
  int g = g0 + gsel;
  int tl0 = wvi * 2 + (grp >> 1);   // position slot within 8-pos step
  int dbase = lig * 8;
  bool hi8 = (lig & 8) != 0, hi4 = (lig & 4) != 0;

  __shared__ float s_wacc[4][2][NREP][HD];
  __shared__ float s_wl[4][2][NREP];

  float qf[4][8];
#pragma unroll
  for (int h = 0; h < 4; ++h)
#pragma unroll
    for (int e = 0; e < 8; ++e)
      qf[h][e] = q_rope[(g * NREP + h) * HD + dbase + e];

  float lsum[4] = {0.f, 0.f, 0.f, 0.f};
  float acc[4][8];
#pragma unroll
  for (int h = 0; h < 4; ++h)
#pragma unroll
    for (int e = 0; e < 8; ++e) acc[h][e] = 0.f;

  const float scale = 0.08838834764831845f;  // 1/sqrt(128)
  int iters = CH >> 3;                        // 8 positions per step
  bool full = (t0 + CH + 8 <= start_pos);     // 1-step prefetch margin
  const size_t kstep = (size_t)8 * NKV * HD;

  if (full) {
    const float* kp = k_cache + ((size_t)(t0 + tl0) * NKV + g) * HD + dbase;
    const float* vp = v_cache + ((size_t)(t0 + tl0) * NKV + g) * HD + dbase;
    f32x4 KA0 = NT4(kp), KB0 = NT4(kp + 4);
    f32x4 VA0 = NT4(vp), VB0 = NT4(vp + 4);
    kp += kstep; vp += kstep;
    for (int i = 0; i < iters; i += 2) {
      f32x4 KA1 = NT4(kp), KB1 = NT4(kp + 4);
      f32x4 VA1 = NT4(vp), VB1 = NT4(vp + 4);
      kp += kstep; vp += kstep;
      __builtin_amdgcn_sched_barrier(0);   // loads above stay above
      STEP(KA0, KB0, VA0, VB0, true);
      KA0 = NT4(kp); KB0 = NT4(kp + 4);
      VA0 = NT4(vp); VB0 = NT4(vp + 4);
      kp += kstep; vp += kstep;
      __builtin_amdgcn_sched_barrier(0);
      STEP(KA1, KB1, VA1, VB1, true);
    }
  } else {
    for (int i = 0; i < iters; ++i) {
      int t = t0 + i * 8 + tl0;
      bool valid = (t < T);
      const float* kp;
      const float* vp;
      if (t < start_pos) {
        kp = k_cache + ((size_t)t * NKV + g) * HD;
        vp = v_cache + ((size_t)t * NKV + g) * HD;
      } else {
        kp = k_new + (size_t)g * HD;   // safe addr also for invalid t
        vp = v_new + (size_t)g * HD;
      }
      f32x4 KA = NT4(kp + dbase), KB = NT4(kp + dbase + 4);
      f32x4 VAx = NT4(vp + dbase), VBx = NT4(vp + dbase + 4);
      STEP(KA, KB, VAx, VBx, valid);
    }
  }

  // ---- combine groups sharing the same g (xor 32: grp0<->grp2, grp1<->grp3)
#pragma unroll
  for (int h = 0; h < 4; ++h) {
    lsum[h] += __shfl_xor(lsum[h], 32, 64);
#pragma unroll
    for (int e = 0; e < 8; ++e) acc[h][e] += __shfl_xor(acc[h][e], 32, 64);
  }
  if (grp < 2) {   // lanes 0-31 hold (gsel, position-combined) partials
#pragma unroll
    for (int h = 0; h < 4; ++h)
#pragma unroll
      for (int e = 0; e < 8; ++e)
        s_wacc[wvi][gsel][h][dbase + e] = acc[h][e];
    if (lig == 0) {
#pragma unroll
      for (int h = 0; h < 4; ++h) s_wl[wvi][gsel][h] = lsum[h];
    }
  }
  __syncthreads();
  // ---- combine the 4 waves, accumulate into global (m=0 -> plain sums) ----
  for (int o = tid; o < 2 * NREP * HD; o += 256) {
    int gs = o >> 9, h = (o >> 7) & 3, d = o & (HD - 1);
    float sum = s_wacc[0][gs][h][d] + s_wacc[1][gs][h][d] +
                s_wacc[2][gs][h][d] + s_wacc[3][gs][h][d];
    atomicAdd(&attn_raw[((g0 + gs) * NREP + h) * HD + d], sum);
  }
  if (tid < 2 * NREP) {
    int gs = tid >> 2, h = tid & 3;
    atomicAdd(&L_raw[(g0 + gs) * NREP + h],
              s_wl[0][gs][h] + s_wl[1][gs][h] + s_wl[2][gs][h] +
                  s_wl[3][gs][h]);
  }
}

// ---------------------------------------------------------------------------
// Kernel 3: out = (attn_raw / L) @ wo.T — normalization folded in.
// ---------------------------------------------------------------------------
__global__ __launch_bounds__(256) void out_gemv_kernel(
    const float* __restrict__ attn_raw, const float* __restrict__ L_raw,
    const float* __restrict__ wo, float* __restrict__ out) {
  __shared__ float s_invL[NH];
  if (threadIdx.x < NH) s_invL[threadIdx.x] = 1.f / L_raw[threadIdx.x];
  __syncthreads();
  int row = blockIdx.x * 4 + (threadIdx.x >> 6);
  int lane = threadIdx.x & 63;
  const float4* a4 = (const float4*)attn_raw;
  const float4* w4 = (const float4*)(wo + (size_t)row * DIM);
  float a = 0.f;
#pragma unroll 4
  for (int c = lane; c < DIM / 4; c += 64) {
    float4 av = a4[c];
    float4 wv = w4[c];
    float il = s_invL[c >> 5];   // head = float4-index / 32
    a += (av.x * wv.x + av.y * wv.y + av.z * wv.z + av.w * wv.w) * il;
  }
  for (int off = 32; off > 0; off >>= 1) a += __shfl_down(a, off, 64);
  if (lane == 0) out[row] = a;
}

extern "C" void kernel_launch(void* const* d_in, const int* in_sizes, int n_in,
                              void* d_out, int out_size, void* d_ws,
                              size_t ws_size, hipStream_t stream) {
  const float* x       = (const float*)d_in[0];
  const float* fc      = (const float*)d_in[1];
  const float* fs      = (const float*)d_in[2];
  const float* k_cache = (const float*)d_in[3];
  const float* v_cache = (const float*)d_in[4];
  const float* wq      = (const float*)d_in[5];
  const float* wk      = (const float*)d_in[6];
  const float* wv      = (const float*)d_in[7];
  const float* wo      = (const float*)d_in[8];
  float* out = (float*)d_out;

  int start_pos = in_sizes[3] / (NKV * HD);  // cache length
  int T = start_pos + 1;
  int CH = ((T + NSPLIT - 1) / NSPLIT + 7) & ~7;  // 128 for T=32768

  float* ws = (float*)d_ws;
  float* q_rope   = ws;            // 4096
  float* k_new    = ws + 4096;     // 1024
  float* v_new    = ws + 5120;     // 1024
  float* attn_raw = ws + 6144;     // 4096 (+32 L_raw, zeroed by qkv block 0)
  float* L_raw    = attn_raw + NH * HD;  // 32

  qkv_rope_kernel<<<768, 256, 0, stream>>>(x, fc, fs, wq, wk, wv, q_rope,
                                           k_new, v_new, attn_raw);
  attn_partial_kernel<<<4 * NSPLIT, 256, 0, stream>>>(
      q_rope, k_cache, v_cache, k_new, v_new, attn_raw, L_raw,
      start_pos, T, CH);
  out_gemv_kernel<<<1024, 256, 0, stream>>>(attn_raw, L_raw, wo, out);
}